// Round 11
// baseline (202.542 us; speedup 1.0000x reference)
//
#include <hip/hip_runtime.h>
#include <math.h>

#define NB 2          // batch
#define LB 32         // blocks
#define BLKN 64       // block size
#define MM 65         // block + router
#define SS (LB*MM)    // 2080
#define DD 512
#define NH 8
#define HD 64
#define FFH 1024
#define ROWS (NB*SS)  // 4160
#define WT_LS 2621440 // bf16 elems per layer of transposed weights

typedef __attribute__((ext_vector_type(8))) short bf16x8;
typedef __attribute__((ext_vector_type(4))) float f32x4;

__device__ __forceinline__ unsigned short f2bf(float f) {
    union { float f; unsigned u; } v; v.f = f;
    unsigned r = (v.u + 0x7FFFu + ((v.u >> 16) & 1u)) >> 16;   // RNE
    return (unsigned short)r;
}
__device__ __forceinline__ float bf2f(unsigned short u) {
    union { unsigned u; float f; } v; v.u = ((unsigned)u) << 16; return v.f;
}

__device__ __forceinline__ void gload_lds16(const unsigned short* g, unsigned short* l) {
    __builtin_amdgcn_global_load_lds((const __attribute__((address_space(1))) unsigned int*)g,
                                     (__attribute__((address_space(3))) unsigned int*)l,
                                     16, 0, 0);
}

// router-row gather: compact row r (0..63) -> global row
__device__ __forceinline__ int grow_map(int r) {
    return (r >> 5) * SS + (r & 31) * MM + BLKN;
}

// ---------------- rmsnorm, wave-per-row (4 rows/WG). FIRST: build h from x/rt ---
// h residual stream is bf16.
template <int FIRST>
__global__ __launch_bounds__(256) void rms4_k(const unsigned short* __restrict__ hsrc,
                                              const float* __restrict__ x,
                                              const float* __restrict__ rt,
                                              const float* __restrict__ w,
                                              unsigned short* __restrict__ hout,
                                              unsigned short* __restrict__ out) {
    int row = blockIdx.x * 4 + (threadIdx.x >> 6);
    int lane = threadIdx.x & 63;
    float v[8];
    if (FIRST) {
        int s = row % SS, b = row / SS;
        int l = s / MM, j = s % MM;
        const float* sp = (j < BLKN) ? x + ((size_t)(b * LB + l) * BLKN + j) * DD : rt;
        float4 a = *(const float4*)(sp + lane * 8);
        float4 bq = *(const float4*)(sp + lane * 8 + 4);
        v[0] = a.x; v[1] = a.y; v[2] = a.z; v[3] = a.w;
        v[4] = bq.x; v[5] = bq.y; v[6] = bq.z; v[7] = bq.w;
    } else {
        bf16x8 h8 = *(const bf16x8*)(hsrc + (size_t)row * DD + lane * 8);
        #pragma unroll
        for (int j = 0; j < 8; ++j) v[j] = bf2f((unsigned short)h8[j]);
    }
    float ss = 0.0f;
    #pragma unroll
    for (int j = 0; j < 8; ++j) ss += v[j] * v[j];
    #pragma unroll
    for (int off = 32; off; off >>= 1) ss += __shfl_xor(ss, off);
    float r = rsqrtf(ss * (1.0f / 512.0f) + 1e-5f);
    float4 w0 = *(const float4*)(w + lane * 8);
    float4 w1 = *(const float4*)(w + lane * 8 + 4);
    float wv[8] = {w0.x, w0.y, w0.z, w0.w, w1.x, w1.y, w1.z, w1.w};
    unsigned short o8[8];
    #pragma unroll
    for (int j = 0; j < 8; ++j) o8[j] = f2bf(v[j] * r * wv[j]);
    *(bf16x8*)(out + (size_t)row * DD + lane * 8) = *(const bf16x8*)o8;
    if (FIRST) {
        unsigned short h8[8];
        #pragma unroll
        for (int j = 0; j < 8; ++j) h8[j] = f2bf(v[j]);
        *(bf16x8*)(hout + (size_t)row * DD + lane * 8) = *(const bf16x8*)h8;
    }
}

// ---------------- all weight transposes in ONE kernel ----------------
__global__ __launch_bounds__(256) void wtrans_all_k(const float* __restrict__ attn_w,
                                                    const float* __restrict__ attn_o_w,
                                                    const float* __restrict__ up_w,
                                                    const float* __restrict__ down_w,
                                                    unsigned short* __restrict__ wt) {
    __shared__ unsigned short T[64][66];
    int wg = blockIdx.x;
    int layer = wg >= 640;
    int r = wg - layer * 640;
    const float* W; int K, N; size_t dstOff; int perm = 0;
    if (r < 192)      { W = attn_w   + (size_t)layer * 512 * 1536; K = 512;  N = 1536; dstOff = 0; }
    else if (r < 256) { W = attn_o_w + (size_t)layer * 512 * 512;  K = 512;  N = 512;  dstOff = 786432;  r -= 192; }
    else if (r < 512) { W = up_w     + (size_t)layer * 512 * 2048; K = 512;  N = 2048; dstOff = 1048576; perm = 1; r -= 256; }
    else              { W = down_w   + (size_t)layer * 1024 * 512; K = 1024; N = 512;  dstOff = 2097152; r -= 512; }
    unsigned short* dst = wt + (size_t)layer * WT_LS + dstOff;
    int ntn = N >> 6;
    int n0 = (r % ntn) * 64, k0 = (r / ntn) * 64;
    int t = threadIdx.x;
    #pragma unroll
    for (int i = 0; i < 16; ++i) {
        int e = t + i * 256;
        int rr = e >> 6, cc = e & 63;
        T[rr][cc] = f2bf(W[(size_t)(k0 + rr) * N + n0 + cc]);
    }
    __syncthreads();
    #pragma unroll
    for (int i = 0; i < 16; ++i) {
        int e = t + i * 256;
        int rr = e >> 6, cc = e & 63;   // rr = n-row, cc = k-col
        int n = n0 + rr;
        int nr = n;
        if (perm) {
            int p = n & 1023;
            nr = ((p >> 4) << 5) | ((n >> 10) << 4) | (p & 15);
        }
        dst[(size_t)nr * K + k0 + cc] = T[cc][rr];
    }
}

// ---------------- bf16 MFMA GEMM, 128x128 tile (for big-grid GEMMs) ------------
template <int ADD, int OBF, int ROPE, int SILU>
__global__ __launch_bounds__(256) void gemm128_k(const unsigned short* __restrict__ A,
                                                 const unsigned short* __restrict__ Wt,
                                                 void* __restrict__ Cp,
                                                 int K, int N, int colOff) {
    __shared__ unsigned short As[128 * 64];
    __shared__ unsigned short Bs[128 * 64];
    int t = threadIdx.x;
    int lane = t & 63, wv = t >> 6;
    int wm = wv >> 1, wn = wv & 1;
    int rowBase = blockIdx.y * 128, colBase = blockIdx.x * 128;
    int c = lane & 15, g = lane >> 4;
    int sw = (c & 7) << 4;

    f32x4 acc[4][4];
    #pragma unroll
    for (int mt = 0; mt < 4; ++mt)
        #pragma unroll
        for (int nt = 0; nt < 4; ++nt) { f32x4 z = {0, 0, 0, 0}; acc[mt][nt] = z; }

    for (int k0 = 0; k0 < K; k0 += 64) {
        __syncthreads();
        #pragma unroll
        for (int i = 0; i < 4; ++i) {
            int e0 = (i * 4 + wv) * 64;
            int e = e0 + lane;
            int row = e >> 3;
            int kb = ((e & 7) << 4) ^ ((row & 7) << 4);
            int gr = rowBase + row; if (gr > ROWS - 1) gr = ROWS - 1;
            gload_lds16(A + (size_t)gr * K + k0 + (kb >> 1), &As[e0 * 8]);
        }
        #pragma unroll
        for (int i = 0; i < 4; ++i) {
            int e0 = (i * 4 + wv) * 64;
            int e = e0 + lane;
            int row = e >> 3;
            int kb = ((e & 7) << 4) ^ ((row & 7) << 4);
            gload_lds16(Wt + (size_t)(colOff + colBase + row) * K + k0 + (kb >> 1), &Bs[e0 * 8]);
        }
        __syncthreads();

        bf16x8 af[4][2], bfr[4][2];
        #pragma unroll
        for (int mt = 0; mt < 4; ++mt)
            #pragma unroll
            for (int hf = 0; hf < 2; ++hf)
                af[mt][hf] = *(const bf16x8*)
                    &As[((wm * 64 + mt * 16 + c) * 128 + ((hf * 64 + g * 16) ^ sw)) >> 1];
        #pragma unroll
        for (int nt = 0; nt < 4; ++nt)
            #pragma unroll
            for (int hf = 0; hf < 2; ++hf)
                bfr[nt][hf] = *(const bf16x8*)
                    &Bs[((wn * 64 + nt * 16 + c) * 128 + ((hf * 64 + g * 16) ^ sw)) >> 1];
        __builtin_amdgcn_s_setprio(1);
        #pragma unroll
        for (int mt = 0; mt < 4; ++mt)
            #pragma unroll
            for (int nt = 0; nt < 4; ++nt) {
                acc[mt][nt] = __builtin_amdgcn_mfma_f32_16x16x32_bf16(af[mt][0], bfr[nt][0], acc[mt][nt], 0, 0, 0);
                acc[mt][nt] = __builtin_amdgcn_mfma_f32_16x16x32_bf16(af[mt][1], bfr[nt][1], acc[mt][nt], 0, 0, 0);
            }
        __builtin_amdgcn_s_setprio(0);
    }

    if (ROPE) {
        int sec = (colOff + colBase + wn * 64) >> 9;   // 0:q 1:k 2:v
        if (sec < 2) {
            #pragma unroll
            for (int mt = 0; mt < 4; ++mt)
                #pragma unroll
                for (int j = 0; j < 4; ++j) {
                    int row = rowBase + wm * 64 + mt * 16 + g * 4 + j;
                    int spos = row % SS;
                    #pragma unroll
                    for (int p = 0; p < 2; ++p) {
                        float jj = (float)(c + p * 16);
                        float inv = exp2f(jj * -0.41524101186092030f); // (1e-4)^(j/32)
                        float fr = (float)spos * inv;
                        float sn, cs; __sincosf(fr, &sn, &cs);
                        float a = acc[mt][p][j], bb = acc[mt][p + 2][j];
                        acc[mt][p][j] = a * cs + bb * sn;
                        acc[mt][p + 2][j] = -a * sn + bb * cs;
                    }
                }
        }
    }

    #pragma unroll
    for (int mt = 0; mt < 4; ++mt)
        #pragma unroll
        for (int j = 0; j < 4; ++j) {
            int row = rowBase + wm * 64 + mt * 16 + g * 4 + j;
            if (row >= ROWS) continue;
            if (SILU) {
                unsigned short* gr = (unsigned short*)Cp + (size_t)row * 1024;
                #pragma unroll
                for (int ntp = 0; ntp < 2; ++ntp) {
                    int npr = colBase + wn * 64 + ntp * 32;
                    int p = ((npr >> 5) << 4) + c;
                    float u1 = acc[mt][2 * ntp][j];
                    float u2 = acc[mt][2 * ntp + 1][j];
                    gr[p] = f2bf((u1 / (1.0f + __expf(-u1))) * u2);
                }
            } else {
                size_t off = (size_t)row * N + colOff + colBase + wn * 64 + c;
                if (OBF) {
                    unsigned short* cr = (unsigned short*)Cp + off;
                    #pragma unroll
                    for (int nt = 0; nt < 4; ++nt) cr[nt * 16] = f2bf(acc[mt][nt][j]);
                } else {
                    float* cr = (float*)Cp + off;
                    #pragma unroll
                    for (int nt = 0; nt < 4; ++nt) {
                        if (ADD) cr[nt * 16] += acc[mt][nt][j];
                        else     cr[nt * 16] = acc[mt][nt][j];
                    }
                }
            }
        }
}

// ---------------- bf16 MFMA GEMM, 64x128 tile, multi-mode -----------------------
// MODE 0: ADD=1: h(bf16) RMW += acc.  ADD=0: f32 store.
// MODE 2: o-router: hr(bf16)[row] = Hsrc(bf16)[grow(row)] + acc.
// MODE 3: down-final: outp(f32)[row] = Hsrc(bf16)[row] + acc.
// MODE 4: up-router: SwiGLU epilogue -> Cp[row*1024 + p] bf16.
template <int MODE, int ADD>
__global__ __launch_bounds__(256) void gemm64_k(const unsigned short* __restrict__ A,
                                                const unsigned short* __restrict__ Wt,
                                                void* __restrict__ Cp,
                                                const unsigned short* __restrict__ Hsrc,
                                                float* __restrict__ outp,
                                                int K, int N) {
    __shared__ unsigned short As[64 * 64];
    __shared__ unsigned short Bs[128 * 64];
    int t = threadIdx.x;
    int lane = t & 63, wv = t >> 6;
    int wm = wv >> 1, wn = wv & 1;
    int rowBase = blockIdx.y * 64, colBase = blockIdx.x * 128;
    int c = lane & 15, g = lane >> 4;
    int sw = (c & 7) << 4;

    f32x4 acc[2][4];
    #pragma unroll
    for (int mt = 0; mt < 2; ++mt)
        #pragma unroll
        for (int nt = 0; nt < 4; ++nt) { f32x4 z = {0, 0, 0, 0}; acc[mt][nt] = z; }

    for (int k0 = 0; k0 < K; k0 += 64) {
        __syncthreads();
        #pragma unroll
        for (int i = 0; i < 2; ++i) {
            int e0 = (i * 4 + wv) * 64;
            int e = e0 + lane;
            int row = e >> 3;
            int kb = ((e & 7) << 4) ^ ((row & 7) << 4);
            int gr = rowBase + row;
            gload_lds16(A + (size_t)gr * K + k0 + (kb >> 1), &As[e0 * 8]);
        }
        #pragma unroll
        for (int i = 0; i < 4; ++i) {
            int e0 = (i * 4 + wv) * 64;
            int e = e0 + lane;
            int row = e >> 3;
            int kb = ((e & 7) << 4) ^ ((row & 7) << 4);
            gload_lds16(Wt + (size_t)(colBase + row) * K + k0 + (kb >> 1), &Bs[e0 * 8]);
        }
        __syncthreads();

        bf16x8 af[2][2], bfr[4][2];
        #pragma unroll
        for (int mt = 0; mt < 2; ++mt)
            #pragma unroll
            for (int hf = 0; hf < 2; ++hf)
                af[mt][hf] = *(const bf16x8*)
                    &As[((wm * 32 + mt * 16 + c) * 128 + ((hf * 64 + g * 16) ^ sw)) >> 1];
        #pragma unroll
        for (int nt = 0; nt < 4; ++nt)
            #pragma unroll
            for (int hf = 0; hf < 2; ++hf)
                bfr[nt][hf] = *(const bf16x8*)
                    &Bs[((wn * 64 + nt * 16 + c) * 128 + ((hf * 64 + g * 16) ^ sw)) >> 1];
        __builtin_amdgcn_s_setprio(1);
        #pragma unroll
        for (int mt = 0; mt < 2; ++mt)
            #pragma unroll
            for (int nt = 0; nt < 4; ++nt) {
                acc[mt][nt] = __builtin_amdgcn_mfma_f32_16x16x32_bf16(af[mt][0], bfr[nt][0], acc[mt][nt], 0, 0, 0);
                acc[mt][nt] = __builtin_amdgcn_mfma_f32_16x16x32_bf16(af[mt][1], bfr[nt][1], acc[mt][nt], 0, 0, 0);
            }
        __builtin_amdgcn_s_setprio(0);
    }

    #pragma unroll
    for (int mt = 0; mt < 2; ++mt)
        #pragma unroll
        for (int j = 0; j < 4; ++j) {
            int row = rowBase + wm * 32 + mt * 16 + g * 4 + j;
            int col = colBase + wn * 64 + c;
            if (MODE == 0) {
                if (ADD) {
                    unsigned short* cr = (unsigned short*)Cp + (size_t)row * N + col;
                    #pragma unroll
                    for (int nt = 0; nt < 4; ++nt)
                        cr[nt * 16] = f2bf(bf2f(cr[nt * 16]) + acc[mt][nt][j]);
                } else {
                    float* cr = (float*)Cp + (size_t)row * N + col;
                    #pragma unroll
                    for (int nt = 0; nt < 4; ++nt) cr[nt * 16] = acc[mt][nt][j];
                }
            } else if (MODE == 2) {
                int gr = grow_map(row);
                unsigned short* cr = (unsigned short*)Cp + (size_t)row * 512 + col;
                const unsigned short* hsr = Hsrc + (size_t)gr * 512 + col;
                #pragma unroll
                for (int nt = 0; nt < 4; ++nt)
                    cr[nt * 16] = f2bf(bf2f(hsr[nt * 16]) + acc[mt][nt][j]);
            } else if (MODE == 3) {
                float* cr = outp + (size_t)row * 512 + col;
                const unsigned short* hsr = Hsrc + (size_t)row * 512 + col;
                #pragma unroll
                for (int nt = 0; nt < 4; ++nt) cr[nt * 16] = bf2f(hsr[nt * 16]) + acc[mt][nt][j];
            } else { // MODE 4: SwiGLU
                unsigned short* gr = (unsigned short*)Cp + (size_t)row * 1024;
                #pragma unroll
                for (int ntp = 0; ntp < 2; ++ntp) {
                    int npr = colBase + wn * 64 + ntp * 32;
                    int p = ((npr >> 5) << 4) + c;
                    float u1 = acc[mt][2 * ntp][j];
                    float u2 = acc[mt][2 * ntp + 1][j];
                    gr[p] = f2bf((u1 / (1.0f + __expf(-u1))) * u2);
                }
            }
        }
}

// ---------------- flash attention (layer 1), bf16 MFMA, 5 waves ----------------
// WG pairing: CU c hosts blockIdx i and i+256 (XCD round-robin). idx<256 -> big l,
// idx>=256 -> small l, so every CU gets one big + one small WG (balanced makespan).
#define QR 80

__global__ __launch_bounds__(320) void attn_mfma_k(const unsigned short* __restrict__ qkv,
                                                   const int* __restrict__ doc,
                                                   unsigned short* __restrict__ o) {
    __shared__ unsigned short Qs[QR * 64];       // XOR-swizzled, 128B rows
    __shared__ unsigned short Ks[2][64 * 64];    // double-buffered, swizzled
    __shared__ unsigned short Vt[2][64][72];     // transposed [d][key], padded
    __shared__ unsigned short Ps[5][16][72];     // wave-private P tiles
    __shared__ int docq[QR];
    __shared__ int dock[2][64];

    int idx = blockIdx.x;
    int l = (idx < 256) ? (31 - (idx >> 4)) : ((idx - 256) >> 4);
    int b = (idx >> 3) & 1;
    int h = idx & 7;
    int t = threadIdx.x;
    int lane = t & 63;
    int wv = t >> 6;

    const unsigned short* qb = qkv + (size_t)b * SS * 1536;
    int rowq0 = l * MM;
    int kmax = (l + 1) * MM;

    #pragma unroll
    for (int it = 0; it < 2; ++it) {
        int ebase = it * 320 + wv * 64;
        int e = ebase + lane;
        int row = e >> 3;
        int kb = ((e & 7) << 4) ^ ((row & 7) << 4);
        int gr = rowq0 + row; if (gr > SS - 1) gr = SS - 1;
        gload_lds16(qb + (size_t)gr * 1536 + h * 64 + (kb >> 1), &Qs[ebase * 8]);
    }
    if (t < QR) docq[t] = (t < MM) ? doc[b * SS + rowq0 + t] : -999999;

    int d0 = doc[b * SS + rowq0];
    int lo = 0, hi = rowq0;
    while (lo < hi) {
        int mid = (lo + hi) >> 1;
        if (doc[b * SS + mid] < d0) lo = mid + 1; else hi = mid;
    }
    int kts = lo >> 6;
    int nkt = (kmax + 63) >> 6;

    const int mt = wv;
    const int g = lane >> 4;
    const int c = lane & 15;
    const int sw = (c & 7) << 4;

    auto stageK = [&](int kbase, int buf) {
        int ebase = wv * 64;
        int e = ebase + lane;
        int row = e >> 3;
        int kb = ((e & 7) << 4) ^ ((row & 7) << 4);
        int kg = kbase + row; if (kg > kmax - 1) kg = kmax - 1;
        gload_lds16(qb + (size_t)kg * 1536 + 512 + h * 64 + (kb >> 1), &Ks[buf][ebase * 8]);
        if (wv < 3) {
            int eb2 = 320 + wv * 64;
            int e2 = eb2 + lane;
            int row2 = e2 >> 3;
            int kb2 = ((e2 & 7) << 4) ^ ((row2 & 7) << 4);
            int kg2 = kbase + row2; if (kg2 > kmax - 1) kg2 = kmax - 1;
            gload_lds16(qb + (size_t)kg2 * 1536 + 512 + h * 64 + (kb2 >> 1), &Ks[buf][eb2 * 8]);
        }
    };
    bf16x8 vr0, vr1; int dnx = 0;
    auto loadV = [&](int kbase) {
        int key = t & 63;
        int de = (t >> 6) * 8;
        int kg = kbase + key; if (kg > kmax - 1) kg = kmax - 1;
        vr0 = *(const bf16x8*)(qb + (size_t)kg * 1536 + 1024 + h * 64 + de);
        if (t < 192) {
            int e2 = 320 + t;
            int key2 = e2 & 63;
            int de2 = (e2 >> 6) * 8;
            int kg2 = kbase + key2; if (kg2 > kmax - 1) kg2 = kmax - 1;
            vr1 = *(const bf16x8*)(qb + (size_t)kg2 * 1536 + 1024 + h * 64 + de2);
        }
        if (t < 64) dnx = (kbase + t < kmax) ? doc[b * SS + kbase + t] : -1000000;
    };
    auto writeV = [&](int buf) {
        int key = t & 63;
        int de = (t >> 6) * 8;
        #pragma unroll
        for (int jj = 0; jj < 8; ++jj) Vt[buf][de + jj][key] = ((unsigned short*)&vr0)[jj];
        if (t < 192) {
            int e2 = 320 + t;
            int key2 = e2 & 63;
            int de2 = (e2 >> 6) * 8;
            #pragma unroll
            for (int jj = 0; jj < 8; ++jj) Vt[buf][de2 + jj][key2] = ((unsigned short*)&vr1)[jj];
        }
        if (t < 64) dock[buf][t] = dnx;
    };

    stageK(kts << 6, 0);
    loadV(kts << 6);
    writeV(0);
    __syncthreads();

    bf16x8 aq[2];
    #pragma unroll
    for (int hf = 0; hf < 2; ++hf)
        aq[hf] = *(const bf16x8*)&Qs[((mt * 16 + c) * 128 + ((hf * 64 + g * 16) ^ sw)) >> 1];
    int dq[4];
    #pragma unroll
    for (int j = 0; j < 4; ++j) dq[j] = docq[mt * 16 + g * 4 + j];

    f32x4 oacc[4];
    float m_[4], l_[4];
    #pragma unroll
    for (int nt = 0; nt < 4; ++nt) { f32x4 z = {0,0,0,0}; oacc[nt] = z; }
    #pragma unroll
    for (int j = 0; j < 4; ++j) { m_[j] = -1e30f; l_[j] = 0.0f; }

    for (int kt = kts; kt < nkt; ++kt) {
        int cur = (kt - kts) & 1;
        bool more = (kt + 1 < nkt);
        if (more) {
            stageK((kt + 1) << 6, cur ^ 1);
            loadV((kt + 1) << 6);
        }

        f32x4 s[4];
        __builtin_amdgcn_s_setprio(1);
        #pragma unroll
        for (int sub = 0; sub < 4; ++sub) {
            f32x4 acc = {0, 0, 0, 0};
            #pragma unroll
            for (int hf = 0; hf < 2; ++hf) {
                bf16x8 bk = *(const bf16x8*)
                    &Ks[cur][((sub * 16 + c) * 128 + ((hf * 64 + g * 16) ^ sw)) >> 1];
                acc = __builtin_amdgcn_mfma_f32_16x16x32_bf16(aq[hf], bk, acc, 0, 0, 0);
            }
            s[sub] = acc;
        }
        __builtin_amdgcn_s_setprio(0);
        #pragma unroll
        for (int sub = 0; sub < 4; ++sub) {
            int dk = dock[cur][sub * 16 + c];
            #pragma unroll
            for (int j = 0; j < 4; ++j)
                s[sub][j] = (dq[j] == dk) ? s[sub][j] * 0.125f : -1e30f;
        }
        float mx[4];
        #pragma unroll
        for (int j = 0; j < 4; ++j)
            mx[j] = fmaxf(fmaxf(s[0][j], s[1][j]), fmaxf(s[2][j], s[3][j]));
        #pragma unroll
        for (int off = 1; off < 16; off <<= 1)
            #pragma unroll
            for (int j = 0; j < 4; ++j) mx[j] = fmaxf(mx[j], __shfl_xor(mx[j], off));
        float mn[4], sc[4], rs[4];
        #pragma unroll
        for (int j = 0; j < 4; ++j) {
            mn[j] = fmaxf(m_[j], mx[j]);
            sc[j] = __expf(m_[j] - mn[j]);
            m_[j] = mn[j];
            rs[j] = 0.0f;
        }
        #pragma unroll
        for (int sub = 0; sub < 4; ++sub)
            #pragma unroll
            for (int j = 0; j < 4; ++j) {
                float p = __expf(s[sub][j] - mn[j]);
                rs[j] += p;
                Ps[wv][g * 4 + j][sub * 16 + c] = f2bf(p);
            }
        #pragma unroll
        for (int off = 1; off < 16; off <<= 1)
            #pragma unroll
            for (int j = 0; j < 4; ++j) rs[j] += __shfl_xor(rs[j], off);
        #pragma unroll
        for (int j = 0; j < 4; ++j) l_[j] = l_[j] * sc[j] + rs[j];
        #pragma unroll
        for (int nt = 0; nt < 4; ++nt)
            #pragma unroll
            for (int j = 0; j < 4; ++j) oacc[nt][j] *= sc[j];
        __builtin_amdgcn_s_setprio(1);
        #pragma unroll
        for (int hf = 0; hf < 2; ++hf) {
            bf16x8 af = *(const bf16x8*)&Ps[wv][c][hf * 32 + g * 8];
            #pragma unroll
            for (int nt = 0; nt < 4; ++nt) {
                bf16x8 bv = *(const bf16x8*)&Vt[cur][nt * 16 + c][hf * 32 + g * 8];
                oacc[nt] = __builtin_amdgcn_mfma_f32_16x16x32_bf16(af, bv, oacc[nt], 0, 0, 0);
            }
        }
        __builtin_amdgcn_s_setprio(0);

        if (more) writeV(cur ^ 1);
        __syncthreads();
    }

    #pragma unroll
    for (int j = 0; j < 4; ++j) {
        int row = mt * 16 + g * 4 + j;
        if (row < MM) {
            float invl = 1.0f / l_[j];
            #pragma unroll
            for (int nt = 0; nt < 4; ++nt)
                o[(size_t)(b * SS + rowq0 + row) * DD + h * 64 + nt * 16 + c] =
                    f2bf(oacc[nt][j] * invl);
        }
    }
}

// ---------------- router attention (layer 2): 4 waves per (b,h,l) --------------
__global__ __launch_bounds__(256) void rattn_k(const unsigned short* __restrict__ hnb,
                                               const unsigned short* __restrict__ qkv,
                                               const unsigned short* __restrict__ wq,
                                               const int* __restrict__ doc,
                                               unsigned short* __restrict__ obr) {
    __shared__ float hn_r[DD];
    __shared__ float qs[HD];
    __shared__ float sc[SS];
    __shared__ float red_m[4], red_s[4];
    __shared__ float pacc[4][HD];

    int idx = blockIdx.x;           // 0..511
    int b = idx >> 8, h = (idx >> 5) & 7, l = idx & 31;
    int t = threadIdx.x;
    int lane = t & 63, wv = t >> 6;

    const unsigned short* qb = qkv + (size_t)b * SS * 1536;
    int spos = l * MM + BLKN;       // router position within sequence
    int rowq = b * SS + spos;
    int kmax = (l + 1) * MM;

    {
        unsigned v = *(const unsigned*)(hnb + (size_t)rowq * DD + t * 2);
        hn_r[t * 2] = bf2f((unsigned short)(v & 0xffff));
        hn_r[t * 2 + 1] = bf2f((unsigned short)(v >> 16));
    }
    int dr = doc[rowq];
    int lo = 0, hi = spos;
    while (lo < hi) {
        int mid = (lo + hi) >> 1;
        if (doc[b * SS + mid] < dr) lo = mid + 1; else hi = mid;
    }
    __syncthreads();

    // q projection: wave wv sums k in [wv*128, wv*128+128); lane = output dim
    {
        float part = 0.0f;
        const unsigned short* wr = wq + (size_t)(h * 64 + lane) * DD + wv * 128;
        #pragma unroll
        for (int k8 = 0; k8 < 16; ++k8) {
            bf16x8 w8 = *(const bf16x8*)(wr + k8 * 8);
            #pragma unroll
            for (int j = 0; j < 8; ++j)
                part += hn_r[wv * 128 + k8 * 8 + j] * bf2f((unsigned short)w8[j]);
        }
        pacc[wv][lane] = part;
    }
    __syncthreads();
    if (wv == 0) {
        float dq = pacc[0][lane] + pacc[1][lane] + pacc[2][lane] + pacc[3][lane];
        float other = __shfl_xor(dq, 32);
        float jj = (float)(lane & 31);
        float inv = exp2f(jj * -0.41524101186092030f);
        float fr = (float)spos * inv;
        float sn, cs; __sincosf(fr, &sn, &cs);
        float q1 = (lane < 32) ? dq : other;
        float q2 = (lane < 32) ? other : dq;
        qs[lane] = (lane < 32) ? (q1 * cs + q2 * sn) : (-q1 * sn + q2 * cs);
    }
    __syncthreads();

    // scores: 32 keys per WG-iter; lane = k8*8 + dc (dc fastest -> coalesced)
    int dc = lane & 7, k8 = lane >> 3;
    float mx = -1e30f;
    for (int k0 = lo; k0 < kmax; k0 += 32) {
        int k = k0 + wv * 8 + k8;
        float d = 0.0f;
        if (k < kmax) {
            bf16x8 kv = *(const bf16x8*)(qb + (size_t)k * 1536 + 512 + h * 64 + dc * 8);
            #pragma unroll
            for (int j = 0; j < 8; ++j)
                d += bf2f((unsigned short)kv[j]) * qs[dc * 8 + j];
        }
        #pragma unroll
        for (int off = 1; off < 8; off <<= 1) d += __shfl_xor(d, off);
        if (k < kmax) {
            float s = d * 0.125f;
            if (dc == 0) sc[k] = s;
            mx = fmaxf(mx, s);
        }
    }
    #pragma unroll
    for (int off = 32; off; off >>= 1) mx = fmaxf(mx, __shfl_xor(mx, off));
    if (lane == 0) red_m[wv] = mx;
    __syncthreads();
    mx = fmaxf(fmaxf(red_m[0], red_m[1]), fmaxf(red_m[2], red_m[3]));

    float sum = 0.0f;
    for (int k = lo + t; k < kmax; k += 256) {
        float p = __expf(sc[k] - mx);
        sc[k] = p;
        sum += p;
    }
    #pragma unroll
    for (int off = 32; off; off >>= 1) sum += __shfl_xor(sum, off);
    if (lane == 0) red_s[wv] = sum;
    __syncthreads();
    sum = red_s[0] + red_s[1] + red_s[2] + red_s[3];

    // PV: wave wv handles keys lo+wv+4i; 4 independent accumulators
    float a0 = 0, a1 = 0, a2 = 0, a3 = 0;
    int k = lo + wv;
    for (; k + 12 < kmax; k += 16) {
        a0 += sc[k]      * bf2f(qb[(size_t)k * 1536 + 1024 + h * 64 + lane]);
        a1 += sc[k + 4]  * bf2f(qb[(size_t)(k + 4) * 1536 + 1024 + h * 64 + lane]);
        a2 += sc[k + 8]  * bf2f(qb[(size_t)(k + 8) * 1536 + 1024 + h * 64 + lane]);
        a3 += sc[k + 12] * bf2f(qb[(size_t)(k + 12) * 1536 + 1024 + h * 64 + lane]);
    }
    for (; k < kmax; k += 4)
        a0 += sc[k] * bf2f(qb[(size_t)k * 1536 + 1024 + h * 64 + lane]);
    pacc[wv][lane] = (a0 + a1) + (a2 + a3);
    __syncthreads();
    if (wv == 0) {
        float o = (pacc[0][lane] + pacc[1][lane] + pacc[2][lane] + pacc[3][lane]) / sum;
        obr[(size_t)(b * LB + l) * DD + h * 64 + lane] = f2bf(o);
    }
}

extern "C" void kernel_launch(void* const* d_in, const int* in_sizes, int n_in,
                              void* d_out, int out_size, void* d_ws, size_t ws_size,
                              hipStream_t stream) {
    const float* x           = (const float*)d_in[0];
    const int*   doc         = (const int*)d_in[1];
    const float* rt          = (const float*)d_in[2];
    const float* attn_w      = (const float*)d_in[3];
    const float* attn_o_w    = (const float*)d_in[4];
    const float* ffn_up_w    = (const float*)d_in[5];
    const float* ffn_down_w  = (const float*)d_in[6];
    const float* attn_norm_w = (const float*)d_in[7];
    const float* ffn_norm_w  = (const float*)d_in[8];
    float* out = (float*)d_out;

    unsigned short* hb   = (unsigned short*)d_ws;                 // ROWS*512 bf16 residual
    unsigned short* qkvb = hb + (size_t)ROWS * 512;               // ROWS*1536 bf16
    unsigned short* wt   = qkvb + (size_t)ROWS * 1536;            // 2*WT_LS bf16
    unsigned short* hnb  = wt + (size_t)2 * WT_LS;                // ROWS*512 bf16
    unsigned short* ob   = hnb + (size_t)ROWS * 512;              // ROWS*512 bf16
    unsigned short* gb   = ob + (size_t)ROWS * 512;               // ROWS*1024 bf16
    unsigned short* obr  = gb + (size_t)ROWS * 1024;              // 64*512 bf16
    unsigned short* hnr  = obr + 64 * 512;                        // 64*512 bf16
    unsigned short* gbr  = hnr + 64 * 512;                        // 64*1024 bf16
    unsigned short* hr   = gbr + 64 * 1024;                       // 64*512 bf16

    wtrans_all_k<<<1280, 256, 0, stream>>>(attn_w, attn_o_w, ffn_up_w, ffn_down_w, wt);

    // ---- layer 1 (full) ----
    rms4_k<1><<<ROWS / 4, 256, 0, stream>>>(hb, x, rt, attn_norm_w, hb, hnb);
    gemm128_k<0, 1, 1, 0><<<dim3(12, 33), 256, 0, stream>>>(hnb, wt, qkvb, 512, 1536, 0);
    attn_mfma_k<<<512, 320, 0, stream>>>(qkvb, doc, ob);
    gemm64_k<0, 1><<<dim3(4, 65), 256, 0, stream>>>(ob, wt + 786432, hb, nullptr, nullptr, 512, 512);
    rms4_k<0><<<ROWS / 4, 256, 0, stream>>>(hb, x, rt, ffn_norm_w, nullptr, hnb);
    gemm128_k<0, 0, 0, 1><<<dim3(16, 33), 256, 0, stream>>>(hnb, wt + 1048576, gb, 512, 2048, 0);
    gemm64_k<0, 1><<<dim3(4, 65), 256, 0, stream>>>(gb, wt + 2097152, hb, nullptr, nullptr, 1024, 512);

    // ---- layer 2 (router-sparse tail) ----
    unsigned short* wl = wt + (size_t)WT_LS;
    rms4_k<0><<<ROWS / 4, 256, 0, stream>>>(hb, x, rt, attn_norm_w + 512, nullptr, hnb);
    gemm128_k<0, 1, 1, 0><<<dim3(8, 33), 256, 0, stream>>>(hnb, wl, qkvb, 512, 1536, 512);   // K,V
    rattn_k<<<512, 256, 0, stream>>>(hnb, qkvb, wl, doc, obr);
    gemm64_k<2, 0><<<dim3(4, 1), 256, 0, stream>>>(obr, wl + 786432, hr, hb, nullptr, 512, 512);
    rms4_k<0><<<16, 256, 0, stream>>>(hr, x, rt, ffn_norm_w + 512, nullptr, hnr);
    gemm64_k<4, 0><<<dim3(16, 1), 256, 0, stream>>>(hnr, wl + 1048576, gbr, nullptr, nullptr, 512, 2048);
    gemm64_k<3, 0><<<dim3(4, 1), 256, 0, stream>>>(gbr, wl + 2097152, nullptr, hr, out, 1024, 512);
}

// Round 12
// 187.272 us; speedup vs baseline: 1.0815x; 1.0815x over previous
//
#include <hip/hip_runtime.h>
#include <math.h>

#define NB 2          // batch
#define LB 32         // blocks
#define BLKN 64       // block size
#define MM 65         // block + router
#define SS (LB*MM)    // 2080
#define DD 512
#define NH 8
#define HD 64
#define FFH 1024
#define ROWS (NB*SS)  // 4160
#define WT_LS 2621440 // bf16 elems per layer of transposed weights

typedef __attribute__((ext_vector_type(8))) short bf16x8;
typedef __attribute__((ext_vector_type(4))) float f32x4;

__device__ __forceinline__ unsigned short f2bf(float f) {
    union { float f; unsigned u; } v; v.f = f;
    unsigned r = (v.u + 0x7FFFu + ((v.u >> 16) & 1u)) >> 16;   // RNE
    return (unsigned short)r;
}
__device__ __forceinline__ float bf2f(unsigned short u) {
    union { unsigned u; float f; } v; v.u = ((unsigned)u) << 16; return v.f;
}

__device__ __forceinline__ void gload_lds16(const unsigned short* g, unsigned short* l) {
    __builtin_amdgcn_global_load_lds((const __attribute__((address_space(1))) unsigned int*)g,
                                     (__attribute__((address_space(3))) unsigned int*)l,
                                     16, 0, 0);
}

// router-row gather: compact row r (0..63) -> global row
__device__ __forceinline__ int grow_map(int r) {
    return (r >> 5) * SS + (r & 31) * MM + BLKN;
}

// ---------------- rmsnorm, wave-per-row (4 rows/WG). FIRST: build h from x/rt ---
// h residual stream is bf16.
template <int FIRST>
__global__ __launch_bounds__(256) void rms4_k(const unsigned short* __restrict__ hsrc,
                                              const float* __restrict__ x,
                                              const float* __restrict__ rt,
                                              const float* __restrict__ w,
                                              unsigned short* __restrict__ hout,
                                              unsigned short* __restrict__ out) {
    int row = blockIdx.x * 4 + (threadIdx.x >> 6);
    int lane = threadIdx.x & 63;
    float v[8];
    if (FIRST) {
        int s = row % SS, b = row / SS;
        int l = s / MM, j = s % MM;
        const float* sp = (j < BLKN) ? x + ((size_t)(b * LB + l) * BLKN + j) * DD : rt;
        float4 a = *(const float4*)(sp + lane * 8);
        float4 bq = *(const float4*)(sp + lane * 8 + 4);
        v[0] = a.x; v[1] = a.y; v[2] = a.z; v[3] = a.w;
        v[4] = bq.x; v[5] = bq.y; v[6] = bq.z; v[7] = bq.w;
    } else {
        bf16x8 h8 = *(const bf16x8*)(hsrc + (size_t)row * DD + lane * 8);
        #pragma unroll
        for (int j = 0; j < 8; ++j) v[j] = bf2f((unsigned short)h8[j]);
    }
    float ss = 0.0f;
    #pragma unroll
    for (int j = 0; j < 8; ++j) ss += v[j] * v[j];
    #pragma unroll
    for (int off = 32; off; off >>= 1) ss += __shfl_xor(ss, off);
    float r = rsqrtf(ss * (1.0f / 512.0f) + 1e-5f);
    float4 w0 = *(const float4*)(w + lane * 8);
    float4 w1 = *(const float4*)(w + lane * 8 + 4);
    float wv[8] = {w0.x, w0.y, w0.z, w0.w, w1.x, w1.y, w1.z, w1.w};
    unsigned short o8[8];
    #pragma unroll
    for (int j = 0; j < 8; ++j) o8[j] = f2bf(v[j] * r * wv[j]);
    *(bf16x8*)(out + (size_t)row * DD + lane * 8) = *(const bf16x8*)o8;
    if (FIRST) {
        unsigned short h8[8];
        #pragma unroll
        for (int j = 0; j < 8; ++j) h8[j] = f2bf(v[j]);
        *(bf16x8*)(hout + (size_t)row * DD + lane * 8) = *(const bf16x8*)h8;
    }
}

// ---------------- all weight transposes in ONE kernel ----------------
__global__ __launch_bounds__(256) void wtrans_all_k(const float* __restrict__ attn_w,
                                                    const float* __restrict__ attn_o_w,
                                                    const float* __restrict__ up_w,
                                                    const float* __restrict__ down_w,
                                                    unsigned short* __restrict__ wt) {
    __shared__ unsigned short T[64][66];
    int wg = blockIdx.x;
    int layer = wg >= 640;
    int r = wg - layer * 640;
    const float* W; int K, N; size_t dstOff; int perm = 0;
    if (r < 192)      { W = attn_w   + (size_t)layer * 512 * 1536; K = 512;  N = 1536; dstOff = 0; }
    else if (r < 256) { W = attn_o_w + (size_t)layer * 512 * 512;  K = 512;  N = 512;  dstOff = 786432;  r -= 192; }
    else if (r < 512) { W = up_w     + (size_t)layer * 512 * 2048; K = 512;  N = 2048; dstOff = 1048576; perm = 1; r -= 256; }
    else              { W = down_w   + (size_t)layer * 1024 * 512; K = 1024; N = 512;  dstOff = 2097152; r -= 512; }
    unsigned short* dst = wt + (size_t)layer * WT_LS + dstOff;
    int ntn = N >> 6;
    int n0 = (r % ntn) * 64, k0 = (r / ntn) * 64;
    int t = threadIdx.x;
    #pragma unroll
    for (int i = 0; i < 16; ++i) {
        int e = t + i * 256;
        int rr = e >> 6, cc = e & 63;
        T[rr][cc] = f2bf(W[(size_t)(k0 + rr) * N + n0 + cc]);
    }
    __syncthreads();
    #pragma unroll
    for (int i = 0; i < 16; ++i) {
        int e = t + i * 256;
        int rr = e >> 6, cc = e & 63;   // rr = n-row, cc = k-col
        int n = n0 + rr;
        int nr = n;
        if (perm) {
            int p = n & 1023;
            nr = ((p >> 4) << 5) | ((n >> 10) << 4) | (p & 15);
        }
        dst[(size_t)nr * K + k0 + cc] = T[cc][rr];
    }
}

// ---------------- bf16 MFMA GEMM, 128x128 tile (for big-grid GEMMs) ------------
template <int ADD, int OBF, int ROPE, int SILU>
__global__ __launch_bounds__(256) void gemm128_k(const unsigned short* __restrict__ A,
                                                 const unsigned short* __restrict__ Wt,
                                                 void* __restrict__ Cp,
                                                 int K, int N, int colOff) {
    __shared__ unsigned short As[128 * 64];
    __shared__ unsigned short Bs[128 * 64];
    int t = threadIdx.x;
    int lane = t & 63, wv = t >> 6;
    int wm = wv >> 1, wn = wv & 1;
    int rowBase = blockIdx.y * 128, colBase = blockIdx.x * 128;
    int c = lane & 15, g = lane >> 4;
    int sw = (c & 7) << 4;

    f32x4 acc[4][4];
    #pragma unroll
    for (int mt = 0; mt < 4; ++mt)
        #pragma unroll
        for (int nt = 0; nt < 4; ++nt) { f32x4 z = {0, 0, 0, 0}; acc[mt][nt] = z; }

    for (int k0 = 0; k0 < K; k0 += 64) {
        __syncthreads();
        #pragma unroll
        for (int i = 0; i < 4; ++i) {
            int e0 = (i * 4 + wv) * 64;
            int e = e0 + lane;
            int row = e >> 3;
            int kb = ((e & 7) << 4) ^ ((row & 7) << 4);
            int gr = rowBase + row; if (gr > ROWS - 1) gr = ROWS - 1;
            gload_lds16(A + (size_t)gr * K + k0 + (kb >> 1), &As[e0 * 8]);
        }
        #pragma unroll
        for (int i = 0; i < 4; ++i) {
            int e0 = (i * 4 + wv) * 64;
            int e = e0 + lane;
            int row = e >> 3;
            int kb = ((e & 7) << 4) ^ ((row & 7) << 4);
            gload_lds16(Wt + (size_t)(colOff + colBase + row) * K + k0 + (kb >> 1), &Bs[e0 * 8]);
        }
        __syncthreads();

        bf16x8 af[4][2], bfr[4][2];
        #pragma unroll
        for (int mt = 0; mt < 4; ++mt)
            #pragma unroll
            for (int hf = 0; hf < 2; ++hf)
                af[mt][hf] = *(const bf16x8*)
                    &As[((wm * 64 + mt * 16 + c) * 128 + ((hf * 64 + g * 16) ^ sw)) >> 1];
        #pragma unroll
        for (int nt = 0; nt < 4; ++nt)
            #pragma unroll
            for (int hf = 0; hf < 2; ++hf)
                bfr[nt][hf] = *(const bf16x8*)
                    &Bs[((wn * 64 + nt * 16 + c) * 128 + ((hf * 64 + g * 16) ^ sw)) >> 1];
        __builtin_amdgcn_s_setprio(1);
        #pragma unroll
        for (int mt = 0; mt < 4; ++mt)
            #pragma unroll
            for (int nt = 0; nt < 4; ++nt) {
                acc[mt][nt] = __builtin_amdgcn_mfma_f32_16x16x32_bf16(af[mt][0], bfr[nt][0], acc[mt][nt], 0, 0, 0);
                acc[mt][nt] = __builtin_amdgcn_mfma_f32_16x16x32_bf16(af[mt][1], bfr[nt][1], acc[mt][nt], 0, 0, 0);
            }
        __builtin_amdgcn_s_setprio(0);
    }

    if (ROPE) {
        int sec = (colOff + colBase + wn * 64) >> 9;   // 0:q 1:k 2:v
        if (sec < 2) {
            #pragma unroll
            for (int mt = 0; mt < 4; ++mt)
                #pragma unroll
                for (int j = 0; j < 4; ++j) {
                    int row = rowBase + wm * 64 + mt * 16 + g * 4 + j;
                    int spos = row % SS;
                    #pragma unroll
                    for (int p = 0; p < 2; ++p) {
                        float jj = (float)(c + p * 16);
                        float inv = exp2f(jj * -0.41524101186092030f); // (1e-4)^(j/32)
                        float fr = (float)spos * inv;
                        float sn, cs; __sincosf(fr, &sn, &cs);
                        float a = acc[mt][p][j], bb = acc[mt][p + 2][j];
                        acc[mt][p][j] = a * cs + bb * sn;
                        acc[mt][p + 2][j] = -a * sn + bb * cs;
                    }
                }
        }
    }

    #pragma unroll
    for (int mt = 0; mt < 4; ++mt)
        #pragma unroll
        for (int j = 0; j < 4; ++j) {
            int row = rowBase + wm * 64 + mt * 16 + g * 4 + j;
            if (row >= ROWS) continue;
            if (SILU) {
                unsigned short* gr = (unsigned short*)Cp + (size_t)row * 1024;
                #pragma unroll
                for (int ntp = 0; ntp < 2; ++ntp) {
                    int npr = colBase + wn * 64 + ntp * 32;
                    int p = ((npr >> 5) << 4) + c;
                    float u1 = acc[mt][2 * ntp][j];
                    float u2 = acc[mt][2 * ntp + 1][j];
                    gr[p] = f2bf((u1 / (1.0f + __expf(-u1))) * u2);
                }
            } else {
                size_t off = (size_t)row * N + colOff + colBase + wn * 64 + c;
                if (OBF) {
                    unsigned short* cr = (unsigned short*)Cp + off;
                    #pragma unroll
                    for (int nt = 0; nt < 4; ++nt) cr[nt * 16] = f2bf(acc[mt][nt][j]);
                } else {
                    float* cr = (float*)Cp + off;
                    #pragma unroll
                    for (int nt = 0; nt < 4; ++nt) {
                        if (ADD) cr[nt * 16] += acc[mt][nt][j];
                        else     cr[nt * 16] = acc[mt][nt][j];
                    }
                }
            }
        }
}

// ---------------- bf16 MFMA GEMM, 64x128 tile, multi-mode -----------------------
// MODE 0: ADD=1: h(bf16) RMW += acc.  ADD=0: f32 store.
// MODE 2: o-router: hr(bf16)[row] = Hsrc(bf16)[grow(row)] + acc.
// MODE 3: down-final: outp(f32)[row] = Hsrc(bf16)[row] + acc.
// MODE 4: up-router: SwiGLU epilogue -> Cp[row*1024 + p] bf16.
template <int MODE, int ADD>
__global__ __launch_bounds__(256) void gemm64_k(const unsigned short* __restrict__ A,
                                                const unsigned short* __restrict__ Wt,
                                                void* __restrict__ Cp,
                                                const unsigned short* __restrict__ Hsrc,
                                                float* __restrict__ outp,
                                                int K, int N) {
    __shared__ unsigned short As[64 * 64];
    __shared__ unsigned short Bs[128 * 64];
    int t = threadIdx.x;
    int lane = t & 63, wv = t >> 6;
    int wm = wv >> 1, wn = wv & 1;
    int rowBase = blockIdx.y * 64, colBase = blockIdx.x * 128;
    int c = lane & 15, g = lane >> 4;
    int sw = (c & 7) << 4;

    f32x4 acc[2][4];
    #pragma unroll
    for (int mt = 0; mt < 2; ++mt)
        #pragma unroll
        for (int nt = 0; nt < 4; ++nt) { f32x4 z = {0, 0, 0, 0}; acc[mt][nt] = z; }

    for (int k0 = 0; k0 < K; k0 += 64) {
        __syncthreads();
        #pragma unroll
        for (int i = 0; i < 2; ++i) {
            int e0 = (i * 4 + wv) * 64;
            int e = e0 + lane;
            int row = e >> 3;
            int kb = ((e & 7) << 4) ^ ((row & 7) << 4);
            int gr = rowBase + row;
            gload_lds16(A + (size_t)gr * K + k0 + (kb >> 1), &As[e0 * 8]);
        }
        #pragma unroll
        for (int i = 0; i < 4; ++i) {
            int e0 = (i * 4 + wv) * 64;
            int e = e0 + lane;
            int row = e >> 3;
            int kb = ((e & 7) << 4) ^ ((row & 7) << 4);
            gload_lds16(Wt + (size_t)(colBase + row) * K + k0 + (kb >> 1), &Bs[e0 * 8]);
        }
        __syncthreads();

        bf16x8 af[2][2], bfr[4][2];
        #pragma unroll
        for (int mt = 0; mt < 2; ++mt)
            #pragma unroll
            for (int hf = 0; hf < 2; ++hf)
                af[mt][hf] = *(const bf16x8*)
                    &As[((wm * 32 + mt * 16 + c) * 128 + ((hf * 64 + g * 16) ^ sw)) >> 1];
        #pragma unroll
        for (int nt = 0; nt < 4; ++nt)
            #pragma unroll
            for (int hf = 0; hf < 2; ++hf)
                bfr[nt][hf] = *(const bf16x8*)
                    &Bs[((wn * 64 + nt * 16 + c) * 128 + ((hf * 64 + g * 16) ^ sw)) >> 1];
        __builtin_amdgcn_s_setprio(1);
        #pragma unroll
        for (int mt = 0; mt < 2; ++mt)
            #pragma unroll
            for (int nt = 0; nt < 4; ++nt) {
                acc[mt][nt] = __builtin_amdgcn_mfma_f32_16x16x32_bf16(af[mt][0], bfr[nt][0], acc[mt][nt], 0, 0, 0);
                acc[mt][nt] = __builtin_amdgcn_mfma_f32_16x16x32_bf16(af[mt][1], bfr[nt][1], acc[mt][nt], 0, 0, 0);
            }
        __builtin_amdgcn_s_setprio(0);
    }

    #pragma unroll
    for (int mt = 0; mt < 2; ++mt)
        #pragma unroll
        for (int j = 0; j < 4; ++j) {
            int row = rowBase + wm * 32 + mt * 16 + g * 4 + j;
            int col = colBase + wn * 64 + c;
            if (MODE == 0) {
                if (ADD) {
                    unsigned short* cr = (unsigned short*)Cp + (size_t)row * N + col;
                    #pragma unroll
                    for (int nt = 0; nt < 4; ++nt)
                        cr[nt * 16] = f2bf(bf2f(cr[nt * 16]) + acc[mt][nt][j]);
                } else {
                    float* cr = (float*)Cp + (size_t)row * N + col;
                    #pragma unroll
                    for (int nt = 0; nt < 4; ++nt) cr[nt * 16] = acc[mt][nt][j];
                }
            } else if (MODE == 2) {
                int gr = grow_map(row);
                unsigned short* cr = (unsigned short*)Cp + (size_t)row * 512 + col;
                const unsigned short* hsr = Hsrc + (size_t)gr * 512 + col;
                #pragma unroll
                for (int nt = 0; nt < 4; ++nt)
                    cr[nt * 16] = f2bf(bf2f(hsr[nt * 16]) + acc[mt][nt][j]);
            } else if (MODE == 3) {
                float* cr = outp + (size_t)row * 512 + col;
                const unsigned short* hsr = Hsrc + (size_t)row * 512 + col;
                #pragma unroll
                for (int nt = 0; nt < 4; ++nt) cr[nt * 16] = bf2f(hsr[nt * 16]) + acc[mt][nt][j];
            } else { // MODE 4: SwiGLU
                unsigned short* gr = (unsigned short*)Cp + (size_t)row * 1024;
                #pragma unroll
                for (int ntp = 0; ntp < 2; ++ntp) {
                    int npr = colBase + wn * 64 + ntp * 32;
                    int p = ((npr >> 5) << 4) + c;
                    float u1 = acc[mt][2 * ntp][j];
                    float u2 = acc[mt][2 * ntp + 1][j];
                    gr[p] = f2bf((u1 / (1.0f + __expf(-u1))) * u2);
                }
            }
        }
}

// ---------------- flash attention (layer 1), bf16 MFMA, 5 waves ----------------
// Qs (prologue-only) and Ps (loop-only) share one LDS buffer -> 3 WGs/CU.
#define QR 80

__global__ __launch_bounds__(320) void attn_mfma_k(const unsigned short* __restrict__ qkv,
                                                   const int* __restrict__ doc,
                                                   unsigned short* __restrict__ o) {
    __shared__ unsigned short QP[5760];          // Qs: 5120 elems | Ps: 5x16x72
    __shared__ unsigned short Ks[2][64 * 64];    // double-buffered, swizzled
    __shared__ unsigned short Vt[2][64][72];     // transposed [d][key], padded
    __shared__ int docq[QR];
    __shared__ int dock[2][64];

    unsigned short* Qs = QP;
    unsigned short (*Ps)[16][72] = (unsigned short (*)[16][72])QP;

    int idx = blockIdx.x;
    int l = (idx < 256) ? (31 - (idx >> 4)) : ((idx - 256) >> 4);
    int b = (idx >> 3) & 1;
    int h = idx & 7;
    int t = threadIdx.x;
    int lane = t & 63;
    int wv = t >> 6;

    const unsigned short* qb = qkv + (size_t)b * SS * 1536;
    int rowq0 = l * MM;
    int kmax = (l + 1) * MM;

    #pragma unroll
    for (int it = 0; it < 2; ++it) {
        int ebase = it * 320 + wv * 64;
        int e = ebase + lane;
        int row = e >> 3;
        int kb = ((e & 7) << 4) ^ ((row & 7) << 4);
        int gr = rowq0 + row; if (gr > SS - 1) gr = SS - 1;
        gload_lds16(qb + (size_t)gr * 1536 + h * 64 + (kb >> 1), &Qs[ebase * 8]);
    }
    if (t < QR) docq[t] = (t < MM) ? doc[b * SS + rowq0 + t] : -999999;

    int d0 = doc[b * SS + rowq0];
    int lo = 0, hi = rowq0;
    while (lo < hi) {
        int mid = (lo + hi) >> 1;
        if (doc[b * SS + mid] < d0) lo = mid + 1; else hi = mid;
    }
    int kts = lo >> 6;
    int nkt = (kmax + 63) >> 6;

    const int mt = wv;
    const int g = lane >> 4;
    const int c = lane & 15;
    const int sw = (c & 7) << 4;

    auto stageK = [&](int kbase, int buf) {
        int ebase = wv * 64;
        int e = ebase + lane;
        int row = e >> 3;
        int kb = ((e & 7) << 4) ^ ((row & 7) << 4);
        int kg = kbase + row; if (kg > kmax - 1) kg = kmax - 1;
        gload_lds16(qb + (size_t)kg * 1536 + 512 + h * 64 + (kb >> 1), &Ks[buf][ebase * 8]);
        if (wv < 3) {
            int eb2 = 320 + wv * 64;
            int e2 = eb2 + lane;
            int row2 = e2 >> 3;
            int kb2 = ((e2 & 7) << 4) ^ ((row2 & 7) << 4);
            int kg2 = kbase + row2; if (kg2 > kmax - 1) kg2 = kmax - 1;
            gload_lds16(qb + (size_t)kg2 * 1536 + 512 + h * 64 + (kb2 >> 1), &Ks[buf][eb2 * 8]);
        }
    };
    bf16x8 vr0, vr1; int dnx = 0;
    auto loadV = [&](int kbase) {
        int key = t & 63;
        int de = (t >> 6) * 8;
        int kg = kbase + key; if (kg > kmax - 1) kg = kmax - 1;
        vr0 = *(const bf16x8*)(qb + (size_t)kg * 1536 + 1024 + h * 64 + de);
        if (t < 192) {
            int e2 = 320 + t;
            int key2 = e2 & 63;
            int de2 = (e2 >> 6) * 8;
            int kg2 = kbase + key2; if (kg2 > kmax - 1) kg2 = kmax - 1;
            vr1 = *(const bf16x8*)(qb + (size_t)kg2 * 1536 + 1024 + h * 64 + de2);
        }
        if (t < 64) dnx = (kbase + t < kmax) ? doc[b * SS + kbase + t] : -1000000;
    };
    auto writeV = [&](int buf) {
        int key = t & 63;
        int de = (t >> 6) * 8;
        #pragma unroll
        for (int jj = 0; jj < 8; ++jj) Vt[buf][de + jj][key] = ((unsigned short*)&vr0)[jj];
        if (t < 192) {
            int e2 = 320 + t;
            int key2 = e2 & 63;
            int de2 = (e2 >> 6) * 8;
            #pragma unroll
            for (int jj = 0; jj < 8; ++jj) Vt[buf][de2 + jj][key2] = ((unsigned short*)&vr1)[jj];
        }
        if (t < 64) dock[buf][t] = dnx;
    };

    stageK(kts << 6, 0);
    loadV(kts << 6);
    writeV(0);
    __syncthreads();

    // hoist Q fragments + query docs into registers (Qs LDS dead afterwards)
    bf16x8 aq[2];
    #pragma unroll
    for (int hf = 0; hf < 2; ++hf)
        aq[hf] = *(const bf16x8*)&Qs[((mt * 16 + c) * 128 + ((hf * 64 + g * 16) ^ sw)) >> 1];
    int dq[4];
    #pragma unroll
    for (int j = 0; j < 4; ++j) dq[j] = docq[mt * 16 + g * 4 + j];
    __syncthreads();   // all waves done reading Qs before Ps overwrites it

    f32x4 oacc[4];
    float m_[4], l_[4];
    #pragma unroll
    for (int nt = 0; nt < 4; ++nt) { f32x4 z = {0,0,0,0}; oacc[nt] = z; }
    #pragma unroll
    for (int j = 0; j < 4; ++j) { m_[j] = -1e30f; l_[j] = 0.0f; }

    for (int kt = kts; kt < nkt; ++kt) {
        int cur = (kt - kts) & 1;
        bool more = (kt + 1 < nkt);
        if (more) {
            stageK((kt + 1) << 6, cur ^ 1);
            loadV((kt + 1) << 6);
        }

        f32x4 s[4];
        __builtin_amdgcn_s_setprio(1);
        #pragma unroll
        for (int sub = 0; sub < 4; ++sub) {
            f32x4 acc = {0, 0, 0, 0};
            #pragma unroll
            for (int hf = 0; hf < 2; ++hf) {
                bf16x8 bk = *(const bf16x8*)
                    &Ks[cur][((sub * 16 + c) * 128 + ((hf * 64 + g * 16) ^ sw)) >> 1];
                acc = __builtin_amdgcn_mfma_f32_16x16x32_bf16(aq[hf], bk, acc, 0, 0, 0);
            }
            s[sub] = acc;
        }
        __builtin_amdgcn_s_setprio(0);
        #pragma unroll
        for (int sub = 0; sub < 4; ++sub) {
            int dk = dock[cur][sub * 16 + c];
            #pragma unroll
            for (int j = 0; j < 4; ++j)
                s[sub][j] = (dq[j] == dk) ? s[sub][j] * 0.125f : -1e30f;
        }
        float mx[4];
        #pragma unroll
        for (int j = 0; j < 4; ++j)
            mx[j] = fmaxf(fmaxf(s[0][j], s[1][j]), fmaxf(s[2][j], s[3][j]));
        #pragma unroll
        for (int off = 1; off < 16; off <<= 1)
            #pragma unroll
            for (int j = 0; j < 4; ++j) mx[j] = fmaxf(mx[j], __shfl_xor(mx[j], off));
        float mn[4], sc[4], rs[4];
        #pragma unroll
        for (int j = 0; j < 4; ++j) {
            mn[j] = fmaxf(m_[j], mx[j]);
            sc[j] = __expf(m_[j] - mn[j]);
            m_[j] = mn[j];
            rs[j] = 0.0f;
        }
        #pragma unroll
        for (int sub = 0; sub < 4; ++sub)
            #pragma unroll
            for (int j = 0; j < 4; ++j) {
                float p = __expf(s[sub][j] - mn[j]);
                rs[j] += p;
                Ps[wv][g * 4 + j][sub * 16 + c] = f2bf(p);
            }
        #pragma unroll
        for (int off = 1; off < 16; off <<= 1)
            #pragma unroll
            for (int j = 0; j < 4; ++j) rs[j] += __shfl_xor(rs[j], off);
        #pragma unroll
        for (int j = 0; j < 4; ++j) l_[j] = l_[j] * sc[j] + rs[j];
        #pragma unroll
        for (int nt = 0; nt < 4; ++nt)
            #pragma unroll
            for (int j = 0; j < 4; ++j) oacc[nt][j] *= sc[j];
        __builtin_amdgcn_s_setprio(1);
        #pragma unroll
        for (int hf = 0; hf < 2; ++hf) {
            bf16x8 af = *(const bf16x8*)&Ps[wv][c][hf * 32 + g * 8];
            #pragma unroll
            for (int nt = 0; nt < 4; ++nt) {
                bf16x8 bv = *(const bf16x8*)&Vt[cur][nt * 16 + c][hf * 32 + g * 8];
                oacc[nt] = __builtin_amdgcn_mfma_f32_16x16x32_bf16(af, bv, oacc[nt], 0, 0, 0);
            }
        }
        __builtin_amdgcn_s_setprio(0);

        if (more) writeV(cur ^ 1);
        __syncthreads();
    }

    #pragma unroll
    for (int j = 0; j < 4; ++j) {
        int row = mt * 16 + g * 4 + j;
        if (row < MM) {
            float invl = 1.0f / l_[j];
            #pragma unroll
            for (int nt = 0; nt < 4; ++nt)
                o[(size_t)(b * SS + rowq0 + row) * DD + h * 64 + nt * 16 + c] =
                    f2bf(oacc[nt][j] * invl);
        }
    }
}

// ---------------- router attention (layer 2): 4 waves per (b,h,l) --------------
__global__ __launch_bounds__(256) void rattn_k(const unsigned short* __restrict__ hnb,
                                               const unsigned short* __restrict__ qkv,
                                               const unsigned short* __restrict__ wq,
                                               const int* __restrict__ doc,
                                               unsigned short* __restrict__ obr) {
    __shared__ float hn_r[DD];
    __shared__ float qs[HD];
    __shared__ float sc[SS];
    __shared__ float red_m[4], red_s[4];
    __shared__ float pacc[4][HD];

    int idx = blockIdx.x;           // 0..511
    int b = idx >> 8, h = (idx >> 5) & 7, l = idx & 31;
    int t = threadIdx.x;
    int lane = t & 63, wv = t >> 6;

    const unsigned short* qb = qkv + (size_t)b * SS * 1536;
    int spos = l * MM + BLKN;       // router position within sequence
    int rowq = b * SS + spos;
    int kmax = (l + 1) * MM;

    {
        unsigned v = *(const unsigned*)(hnb + (size_t)rowq * DD + t * 2);
        hn_r[t * 2] = bf2f((unsigned short)(v & 0xffff));
        hn_r[t * 2 + 1] = bf2f((unsigned short)(v >> 16));
    }
    int dr = doc[rowq];
    int lo = 0, hi = spos;
    while (lo < hi) {
        int mid = (lo + hi) >> 1;
        if (doc[b * SS + mid] < dr) lo = mid + 1; else hi = mid;
    }
    __syncthreads();

    // q projection: wave wv sums k in [wv*128, wv*128+128); lane = output dim
    {
        float part = 0.0f;
        const unsigned short* wr = wq + (size_t)(h * 64 + lane) * DD + wv * 128;
        #pragma unroll
        for (int k8 = 0; k8 < 16; ++k8) {
            bf16x8 w8 = *(const bf16x8*)(wr + k8 * 8);
            #pragma unroll
            for (int j = 0; j < 8; ++j)
                part += hn_r[wv * 128 + k8 * 8 + j] * bf2f((unsigned short)w8[j]);
        }
        pacc[wv][lane] = part;
    }
    __syncthreads();
    if (wv == 0) {
        float dq = pacc[0][lane] + pacc[1][lane] + pacc[2][lane] + pacc[3][lane];
        float other = __shfl_xor(dq, 32);
        float jj = (float)(lane & 31);
        float inv = exp2f(jj * -0.41524101186092030f);
        float fr = (float)spos * inv;
        float sn, cs; __sincosf(fr, &sn, &cs);
        float q1 = (lane < 32) ? dq : other;
        float q2 = (lane < 32) ? other : dq;
        qs[lane] = (lane < 32) ? (q1 * cs + q2 * sn) : (-q1 * sn + q2 * cs);
    }
    __syncthreads();

    // scores: 32 keys per WG-iter; lane = k8*8 + dc (dc fastest -> coalesced)
    int dc = lane & 7, k8 = lane >> 3;
    float mx = -1e30f;
    for (int k0 = lo; k0 < kmax; k0 += 32) {
        int k = k0 + wv * 8 + k8;
        float d = 0.0f;
        if (k < kmax) {
            bf16x8 kv = *(const bf16x8*)(qb + (size_t)k * 1536 + 512 + h * 64 + dc * 8);
            #pragma unroll
            for (int j = 0; j < 8; ++j)
                d += bf2f((unsigned short)kv[j]) * qs[dc * 8 + j];
        }
        #pragma unroll
        for (int off = 1; off < 8; off <<= 1) d += __shfl_xor(d, off);
        if (k < kmax) {
            float s = d * 0.125f;
            if (dc == 0) sc[k] = s;
            mx = fmaxf(mx, s);
        }
    }
    #pragma unroll
    for (int off = 32; off; off >>= 1) mx = fmaxf(mx, __shfl_xor(mx, off));
    if (lane == 0) red_m[wv] = mx;
    __syncthreads();
    mx = fmaxf(fmaxf(red_m[0], red_m[1]), fmaxf(red_m[2], red_m[3]));

    float sum = 0.0f;
    for (int k = lo + t; k < kmax; k += 256) {
        float p = __expf(sc[k] - mx);
        sc[k] = p;
        sum += p;
    }
    #pragma unroll
    for (int off = 32; off; off >>= 1) sum += __shfl_xor(sum, off);
    if (lane == 0) red_s[wv] = sum;
    __syncthreads();
    sum = red_s[0] + red_s[1] + red_s[2] + red_s[3];

    // PV: wave wv handles keys lo+wv+4i; 4 independent accumulators
    float a0 = 0, a1 = 0, a2 = 0, a3 = 0;
    int k = lo + wv;
    for (; k + 12 < kmax; k += 16) {
        a0 += sc[k]      * bf2f(qb[(size_t)k * 1536 + 1024 + h * 64 + lane]);
        a1 += sc[k + 4]  * bf2f(qb[(size_t)(k + 4) * 1536 + 1024 + h * 64 + lane]);
        a2 += sc[k + 8]  * bf2f(qb[(size_t)(k + 8) * 1536 + 1024 + h * 64 + lane]);
        a3 += sc[k + 12] * bf2f(qb[(size_t)(k + 12) * 1536 + 1024 + h * 64 + lane]);
    }
    for (; k < kmax; k += 4)
        a0 += sc[k] * bf2f(qb[(size_t)k * 1536 + 1024 + h * 64 + lane]);
    pacc[wv][lane] = (a0 + a1) + (a2 + a3);
    __syncthreads();
    if (wv == 0) {
        float o = (pacc[0][lane] + pacc[1][lane] + pacc[2][lane] + pacc[3][lane]) / sum;
        obr[(size_t)(b * LB + l) * DD + h * 64 + lane] = f2bf(o);
    }
}

extern "C" void kernel_launch(void* const* d_in, const int* in_sizes, int n_in,
                              void* d_out, int out_size, void* d_ws, size_t ws_size,
                              hipStream_t stream) {
    const float* x           = (const float*)d_in[0];
    const int*   doc         = (const int*)d_in[1];
    const float* rt          = (const float*)d_in[2];
    const float* attn_w      = (const float*)d_in[3];
    const float* attn_o_w    = (const float*)d_in[4];
    const float* ffn_up_w    = (const float*)d_in[5];
    const float* ffn_down_w  = (const float*)d_in[6];
    const float* attn_norm_w = (const float*)d_in[7];
    const float* ffn_norm_w  = (const float*)d_in[8];
    float* out = (float*)d_out;

    unsigned short* hb   = (unsigned short*)d_ws;                 // ROWS*512 bf16 residual
    unsigned short* qkvb = hb + (size_t)ROWS * 512;               // ROWS*1536 bf16
    unsigned short* wt   = qkvb + (size_t)ROWS * 1536;            // 2*WT_LS bf16
    unsigned short* hnb  = wt + (size_t)2 * WT_LS;                // ROWS*512 bf16
    unsigned short* ob   = hnb + (size_t)ROWS * 512;              // ROWS*512 bf16
    unsigned short* gb   = ob + (size_t)ROWS * 512;               // ROWS*1024 bf16
    unsigned short* obr  = gb + (size_t)ROWS * 1024;              // 64*512 bf16
    unsigned short* hnr  = obr + 64 * 512;                        // 64*512 bf16
    unsigned short* gbr  = hnr + 64 * 512;                        // 64*1024 bf16
    unsigned short* hr   = gbr + 64 * 1024;                       // 64*512 bf16

    wtrans_all_k<<<1280, 256, 0, stream>>>(attn_w, attn_o_w, ffn_up_w, ffn_down_w, wt);

    // ---- layer 1 (full) ----
    rms4_k<1><<<ROWS / 4, 256, 0, stream>>>(hb, x, rt, attn_norm_w, hb, hnb);
    gemm128_k<0, 1, 1, 0><<<dim3(12, 33), 256, 0, stream>>>(hnb, wt, qkvb, 512, 1536, 0);
    attn_mfma_k<<<512, 320, 0, stream>>>(qkvb, doc, ob);
    gemm64_k<0, 1><<<dim3(4, 65), 256, 0, stream>>>(ob, wt + 786432, hb, nullptr, nullptr, 512, 512);
    rms4_k<0><<<ROWS / 4, 256, 0, stream>>>(hb, x, rt, ffn_norm_w, nullptr, hnb);
    gemm128_k<0, 0, 0, 1><<<dim3(16, 33), 256, 0, stream>>>(hnb, wt + 1048576, gb, 512, 2048, 0);
    gemm64_k<0, 1><<<dim3(4, 65), 256, 0, stream>>>(gb, wt + 2097152, hb, nullptr, nullptr, 1024, 512);

    // ---- layer 2 (router-sparse tail) ----
    unsigned short* wl = wt + (size_t)WT_LS;
    rms4_k<0><<<ROWS / 4, 256, 0, stream>>>(hb, x, rt, attn_norm_w + 512, nullptr, hnb);
    gemm128_k<0, 1, 1, 0><<<dim3(8, 33), 256, 0, stream>>>(hnb, wl, qkvb, 512, 1536, 512);   // K,V
    rattn_k<<<512, 256, 0, stream>>>(hnb, qkvb, wl, doc, obr);
    gemm64_k<2, 0><<<dim3(4, 1), 256, 0, stream>>>(obr, wl + 786432, hr, hb, nullptr, 512, 512);
    rms4_k<0><<<16, 256, 0, stream>>>(hr, x, rt, ffn_norm_w + 512, nullptr, hnr);
    gemm64_k<4, 0><<<dim3(16, 1), 256, 0, stream>>>(hnr, wl + 1048576, gbr, nullptr, nullptr, 512, 2048);
    gemm64_k<3, 0><<<dim3(4, 1), 256, 0, stream>>>(gbr, wl + 2097152, nullptr, hr, out, 1024, 512);
}